// Round 2
// baseline (7621.597 us; speedup 1.0000x reference)
//
#include <hip/hip_runtime.h>
#include <math.h>

#define B 128
#define T 128
#define H 128
#define RH 4
#define M 64
#define W 128
#define VOCAB 512
#define IFACE 919
#define G4 512
#define DELTA 1e-6f
#define CLIPV 20.0f

#define MEMLD 132   // mem row stride (W=128 + 4)
#define LNKLD 67    // link row stride (M=64 + 3)

__device__ __forceinline__ float sigmoidf_(float x){ return 1.0f/(1.0f+expf(-x)); }
__device__ __forceinline__ float softplusf_(float x){
  return fmaxf(x, 0.0f) + log1pf(expf(-fabsf(x)));
}
__device__ __forceinline__ float waveAllSum(float v){
  for (int off=1; off<64; off<<=1) v += __shfl_xor(v, off, 64);
  return v;
}
__device__ __forceinline__ float waveAllMax(float v){
  for (int off=1; off<64; off<<=1) v = fmaxf(v, __shfl_xor(v, off, 64));
  return v;
}

__global__ void k_transpose(const float* __restrict__ in, float* __restrict__ out,
                            int rows, int cols, int use_cols){
  int idx = blockIdx.x*blockDim.x + threadIdx.x;
  int total = rows*use_cols;
  if (idx < total){
    int r = idx / use_cols, c = idx - r*use_cols;
    out[c*rows + r] = in[r*cols + c];
  }
}

__global__ void k_xw0(const float* __restrict__ emb, const float* __restrict__ wih0T,
                      const float* __restrict__ b_ih0, const float* __restrict__ b_hh0,
                      float* __restrict__ xw0){
  __shared__ float e[H];
  int v = blockIdx.x, g = threadIdx.x;
  if (g < H) e[g] = emb[v*H + g];
  __syncthreads();
  float acc = b_ih0[g] + b_hh0[g];
  #pragma unroll 8
  for (int k=0;k<H;k++) acc += e[k]*wih0T[k*G4 + g];
  xw0[v*G4 + g] = acc;
}

// Y[bt][o] = b_out[o] + sum_k stash[bt][k] * woutT[k][o]   (16 rows/block)
__launch_bounds__(512, 2)
__global__ void k_out(const float* __restrict__ stash, const float* __restrict__ woutT,
                      const float* __restrict__ b_out, float* __restrict__ Ybuf){
  int o = threadIdx.x & 127, rr = threadIdx.x >> 7;
  long base = (long)blockIdx.x*16 + rr*4;
  float a0=0.f,a1=0.f,a2=0.f,a3=0.f;
  const float* s0 = stash + base*640;
  #pragma unroll 4
  for (int k=0;k<640;k++){
    float w = woutT[k*H + o];
    a0 += s0[k]*w; a1 += s0[640+k]*w; a2 += s0[1280+k]*w; a3 += s0[1920+k]*w;
  }
  float bo = b_out[o];
  Ybuf[(base+0)*H + o] = a0 + bo;
  Ybuf[(base+1)*H + o] = a1 + bo;
  Ybuf[(base+2)*H + o] = a2 + bo;
  Ybuf[(base+3)*H + o] = a3 + bo;
}

// out[b][v][t] = b_fc[v] + sum_k Ybuf[b*T+t][k] * w_fc[v][k]
__launch_bounds__(512, 1)
__global__ void k_logits(const float* __restrict__ Ybuf, const float* __restrict__ w_fc,
                         const float* __restrict__ b_fc, float* __restrict__ out){
  int b = blockIdx.x;
  int t = threadIdx.x & 127, vg = threadIdx.x >> 7;
  float4 y[32];
  const float4* yp = (const float4*)(Ybuf + ((long)b*T + t)*H);
  #pragma unroll
  for (int i=0;i<32;i++) y[i] = yp[i];
  for (int vv=0; vv<128; ++vv){
    int v = vg*128 + vv;
    const float4* wp = (const float4*)(w_fc + (long)v*H);
    float acc = b_fc[v];
    #pragma unroll 8
    for (int i=0;i<32;i++){
      float4 w = wp[i];
      acc += y[i].x*w.x + y[i].y*w.y + y[i].z*w.z + y[i].w*w.w;
    }
    out[((size_t)b*VOCAB + v)*T + t] = acc;
  }
}

__launch_bounds__(1024, 1)
__global__ void k_dnc(const int* __restrict__ tokens,
                      const float* __restrict__ xw0,
                      const float* __restrict__ whh0T,
                      const float* __restrict__ w1catT,
                      const float* __restrict__ b_ih1,
                      const float* __restrict__ b_hh1,
                      const float* __restrict__ wifaceT,
                      const float* __restrict__ b_iface,
                      const float* __restrict__ woutT,
                      const float* __restrict__ b_out,
                      const float* __restrict__ wfcT,
                      const float* __restrict__ b_fc,
                      const float* __restrict__ h0,
                      float* __restrict__ out,
                      float* __restrict__ stash,
                      int defer)
{
  const int b = blockIdx.x;
  const int tid = threadIdx.x;
  const int lane = tid & 63;
  const int wave = tid >> 6;

  __shared__ float h0s[H], c0s[H], h1s[H], c1s[H];
  __shared__ float mem[M*MEMLD];
  __shared__ float link[M*LNKLD];
  __shared__ float prec[M], ww[M], usage[M];
  __shared__ float rw[RH*M];
  __shared__ float gates[G4];
  __shared__ float xi[IFACE+1];
  __shared__ float outv[H];
  __shared__ float rk[RH*W];
  __shared__ float wk[W], er[W], wv[W];
  __shared__ float rvec[RH*W];
  __shared__ float memnorm[M];
  __shared__ float wcw[M], alloc_s[M];
  __shared__ float cwm[RH*M], fwd[RH*M], bwd[RH*M];
  __shared__ float red[1024];
  __shared__ float rstr[RH], fg[RH], rmode[RH*3];
  __shared__ float s_wstr, s_ag, s_wg, s_wwsum, s_wkinv, s_rkinv[RH];

  if (tid < H){
    float hv0 = h0[0*B*H + b*H + tid];
    float hv1 = h0[1*B*H + b*H + tid];
    h0s[tid]=hv0; c0s[tid]=hv0; h1s[tid]=hv1; c1s[tid]=hv1;
  }
  for (int i = tid; i < M*MEMLD; i += 1024) mem[i]=0.f;
  for (int i = tid; i < M*LNKLD; i += 1024) link[i]=0.f;
  if (tid < M){ prec[tid]=0.f; ww[tid]=0.f; usage[tid]=0.f; }
  if (tid < RH*M) rw[tid]=0.f;
  __syncthreads();

  const int colh = tid >> 1;   // 0..511
  const int kh   = tid & 1;    // pair k-split

  for (int t = 0; t < T; ++t){
    const int token = tokens[b*T + t];

    // ---- LSTM0 gates: xw0[token] + h0 @ w_hh0^T  (pair k-split: 64 MACs each)
    {
      float acc = kh ? 0.f : xw0[token*G4 + colh];
      const float* wp = whh0T + (kh*64)*G4 + colh;
      const float* hp = h0s + kh*64;
      #pragma unroll 8
      for (int k=0;k<64;k++) acc += hp[k]*wp[k*G4];
      acc += __shfl_down(acc, 1, 2);
      if (!kh) gates[colh] = acc;
    }
    __syncthreads();
    if (tid < H){
      float ig = sigmoidf_(gates[tid]);
      float ff = sigmoidf_(gates[H+tid]);
      float gg = tanhf(gates[2*H+tid]);
      float og = sigmoidf_(gates[3*H+tid]);
      float c2 = ff*c0s[tid] + ig*gg;
      c0s[tid] = c2;
      h0s[tid] = og*tanhf(c2);
    }
    __syncthreads();

    // ---- LSTM1 gates: [h0,h1] @ w1cat^T  (split halves across pair)
    {
      float acc = kh ? 0.f : (b_ih1[colh] + b_hh1[colh]);
      const float* wp = w1catT + (kh*128)*G4 + colh;
      const float* hp = kh ? h1s : h0s;
      #pragma unroll 8
      for (int k=0;k<128;k++) acc += hp[k]*wp[k*G4];
      acc += __shfl_down(acc, 1, 2);
      if (!kh) gates[colh] = acc;
    }
    __syncthreads();
    if (tid < H){
      float ig = sigmoidf_(gates[tid]);
      float ff = sigmoidf_(gates[H+tid]);
      float gg = tanhf(gates[2*H+tid]);
      float og = sigmoidf_(gates[3*H+tid]);
      float c2 = ff*c1s[tid] + ig*gg;
      c1s[tid] = c2;
      float h2 = og*tanhf(c2);
      h1s[tid] = h2;
      outv[tid] = fminf(fmaxf(h2, -CLIPV), CLIPV);
    }
    __syncthreads();

    // ---- interface vector (one output per thread, 919 active)
    if (tid < IFACE){
      float acc = b_iface[tid];
      const float* wp = wifaceT + tid;
      #pragma unroll 8
      for (int k=0;k<H;k++) acc += outv[k]*wp[k*IFACE];
      xi[tid] = acc;
    }
    __syncthreads();

    // ---- parse interface
    if (tid < RH*W) rk[tid] = tanhf(xi[tid]);
    if (tid >= 512 && tid < 512+W){
      int j = tid - 512;
      wk[j] = tanhf(xi[516+j]);
      er[j] = sigmoidf_(xi[645+j]);
      wv[j] = tanhf(xi[773+j]);
    }
    if (tid >= 640 && tid < 640+RH){
      int r = tid - 640;
      rstr[r] = softplusf_(xi[512+r]);
      fg[r]   = sigmoidf_(xi[901+r]);
      float a0 = xi[907+3*r], a1 = xi[908+3*r], a2 = xi[909+3*r];
      float mx = fmaxf(a0, fmaxf(a1,a2));
      float e0=expf(a0-mx), e1=expf(a1-mx), e2=expf(a2-mx);
      float s = e0+e1+e2;
      rmode[3*r]=e0/s; rmode[3*r+1]=e1/s; rmode[3*r+2]=e2/s;
    }
    if (tid == 704){
      s_wstr = softplusf_(xi[644]);
      s_ag = sigmoidf_(xi[905]);
      s_wg = sigmoidf_(xi[906]);
    }
    __syncthreads();

    // ---- Phase A: usage update (prev ww/rw) + pre-write mem row norms
    if (tid < 512){
      int row = tid >> 3, sub = tid & 7;
      float ss = 0.f;
      #pragma unroll
      for (int i=0;i<16;i++){ float v = mem[row*MEMLD + sub + 8*i]; ss += v*v; }
      ss += __shfl_down(ss,4,8); ss += __shfl_down(ss,2,8); ss += __shfl_down(ss,1,8);
      if (sub==0) memnorm[row] = 1.0f/(sqrtf(ss)+DELTA);
    } else if (tid < 512+M){
      int m = tid - 512;
      float um = usage[m] + (1.0f-usage[m])*ww[m];
      float psi = 1.0f;
      #pragma unroll
      for (int r=0;r<RH;r++) psi *= (1.0f - fg[r]*rw[r*M+m]);
      usage[m] = um*psi;
    } else if (wave >= 10 && wave <= 14){
      // key norms in parallel
      int r = wave - 11;  // wave10 -> write key, waves 11..14 -> read keys
      if (wave == 10){
        float v0 = wk[lane], v1 = wk[lane+64];
        float ss = waveAllSum(v0*v0+v1*v1);
        if (lane==0) s_wkinv = 1.0f/(sqrtf(ss)+DELTA);
      } else {
        float v0 = rk[r*W+lane], v1 = rk[r*W+lane+64];
        float ss = waveAllSum(v0*v0+v1*v1);
        if (lane==0) s_rkinv[r] = 1.0f/(sqrtf(ss)+DELTA);
      }
    }
    __syncthreads();

    // ---- Phase C: write content scores (pre-write memory), 16-way k-split
    {
      int m = tid >> 4, sub = tid & 15;
      float d = 0.f;
      #pragma unroll
      for (int i=0;i<8;i++){ int e = sub + 16*i; d += mem[m*MEMLD + e]*wk[e]; }
      d += __shfl_down(d,8,16); d += __shfl_down(d,4,16); d += __shfl_down(d,2,16); d += __shfl_down(d,1,16);
      if (sub==0) wcw[m] = d * memnorm[m] * s_wkinv * s_wstr;
    }
    __syncthreads();

    // ---- Phase D: wave0 softmax(wcw); wave1 allocation (bitonic argsort)
    if (wave == 0){
      float x = wcw[lane];
      float mx = waveAllMax(x);
      float e = expf(x-mx);
      float s = waveAllSum(e);
      wcw[lane] = e/s;
    } else if (wave == 1){
      float u = DELTA + (1.0f-DELTA)*usage[lane];
      int idx = lane;
      for (int k=2;k<=64;k<<=1){
        for (int j=k>>1;j>0;j>>=1){
          float ou = __shfl_xor(u, j, 64);
          int   oi = __shfl_xor(idx, j, 64);
          bool up = ((lane & k) == 0);
          bool iLower = ((lane & j) == 0);
          bool otherLess = (ou < u) || (ou == u && oi < idx);
          bool takeOther = (up == iLower) ? otherLess : !otherLess;
          if (takeOther){ u = ou; idx = oi; }
        }
      }
      float p = u;
      for (int d=1; d<64; d<<=1){
        float pv = __shfl_up(p, d, 64);
        if (lane >= d) p *= pv;
      }
      float ep = __shfl_up(p, 1, 64);
      if (lane == 0) ep = 1.0f;
      alloc_s[idx] = (1.0f - u) * ep;
    }
    __syncthreads();

    // ---- Phase E: write weights + sum
    if (tid < M){
      float wwm = s_wg*(s_ag*alloc_s[tid] + (1.0f-s_ag)*wcw[tid]);
      ww[tid] = wwm;
      float s = waveAllSum(wwm);
      if (lane==0) s_wwsum = s;
    }
    __syncthreads();

    // ---- Phase F: memory write + link update (old prec)
    #pragma unroll
    for (int e=0;e<8;e++){
      int f = tid + 1024*e;
      int m = f >> 7, w = f & 127;
      mem[m*MEMLD+w] = mem[m*MEMLD+w]*(1.0f - ww[m]*er[w]) + ww[m]*wv[w];
    }
    #pragma unroll
    for (int e=0;e<4;e++){
      int f = tid + 1024*e;
      int i = f >> 6, j = f & 63;
      float lv = (1.0f - ww[i] - ww[j])*link[i*LNKLD+j] + ww[i]*prec[j];
      link[i*LNKLD+j] = (i==j) ? 0.0f : lv;
    }
    __syncthreads();

    // ---- Phase G: precedence update + post-write mem norms
    if (tid < 512){
      int row = tid >> 3, sub = tid & 7;
      float ss = 0.f;
      #pragma unroll
      for (int i=0;i<16;i++){ float v = mem[row*MEMLD + sub + 8*i]; ss += v*v; }
      ss += __shfl_down(ss,4,8); ss += __shfl_down(ss,2,8); ss += __shfl_down(ss,1,8);
      if (sub==0) memnorm[row] = 1.0f/(sqrtf(ss)+DELTA);
    } else if (tid < 512+M){
      int m = tid - 512;
      prec[m] = (1.0f - s_wwsum)*prec[m] + ww[m];
    }
    __syncthreads();

    // ---- Phase H: read content scores (post-write memory), 4-way k-split
    {
      int r = tid >> 8, m = (tid >> 2) & 63, sub = tid & 3;
      float d = 0.f;
      #pragma unroll 8
      for (int i=0;i<32;i++){ int e = sub + 4*i; d += mem[m*MEMLD + e]*rk[r*W + e]; }
      d += __shfl_down(d,2,4); d += __shfl_down(d,1,4);
      if (sub==0) cwm[r*M+m] = d * memnorm[m] * s_rkinv[r] * rstr[r];
    }
    __syncthreads();

    // ---- Phase I: per-head softmax over M
    if (wave < RH){
      int r = wave;
      float x = cwm[r*M + lane];
      float mx = waveAllMax(x);
      float e = expf(x-mx);
      float s = waveAllSum(e);
      cwm[r*M+lane] = e/s;
    }
    __syncthreads();

    // ---- Phase J: fwd/bwd via link (old rw), pair k-split
    if (tid < 512){
      int q = tid >> 1, sub = tid & 1;
      int r = q >> 6, i = q & 63;
      float a = 0.f;
      #pragma unroll 8
      for (int jj=0;jj<32;jj++){ int j = sub + 2*jj; a += link[i*LNKLD+j]*rw[r*M+j]; }
      a += __shfl_down(a,1,2);
      if (sub==0) fwd[r*M+i] = a;
    } else {
      int q = (tid-512) >> 1, sub = tid & 1;
      int r = q >> 6, j = q & 63;
      float a = 0.f;
      #pragma unroll 8
      for (int ii=0;ii<32;ii++){ int i = sub + 2*ii; a += rw[r*M+i]*link[i*LNKLD+j]; }
      a += __shfl_down(a,1,2);
      if (sub==0) bwd[r*M+j] = a;
    }
    __syncthreads();

    // ---- Phase K: read weights update
    if (tid < RH*M){
      int r = tid >> 6;
      rw[tid] = rmode[3*r]*bwd[tid] + rmode[3*r+1]*fwd[tid] + rmode[3*r+2]*cwm[tid];
    }
    __syncthreads();

    // ---- Phase L: read vectors, pair k-split
    {
      int r = tid >> 8, x = tid & 255;
      int w = x >> 1, sub = x & 1;
      float a = 0.f;
      #pragma unroll 8
      for (int mm=0;mm<32;mm++){ int m = sub + 2*mm; a += rw[r*M+m]*mem[m*MEMLD+w]; }
      a += __shfl_down(a,1,2);
      if (sub==0) rvec[r*W+w] = a;
    }
    __syncthreads();

    if (defer){
      // stash [outv, rvec] for deferred tail GEMMs
      if (tid < 640){
        float v = (tid < H) ? outv[tid] : rvec[tid-H];
        stash[((long)(b*T + t))*640 + tid] = v;
      }
      __syncthreads();
    } else {
      // ---- Phase M: y = [out, rvec] @ w_out^T + b_out (8-way k-split)
      {
        int o = tid & 127, c = tid >> 7;
        float a = 0.f;
        int k0 = c*80;
        #pragma unroll 8
        for (int k=k0;k<k0+80;k++){
          float v = (k < H) ? outv[k] : rvec[k-H];
          a += v * woutT[k*H + o];
        }
        red[tid] = a;
      }
      __syncthreads();
      if (tid < H){
        float a = b_out[tid];
        #pragma unroll
        for (int c=0;c<8;c++) a += red[c*128 + tid];
        gates[tid] = a;
      }
      __syncthreads();
      // ---- Phase O: logits, pair k-split
      {
        float a = kh ? 0.f : b_fc[colh];
        const float* wp = wfcT + (kh*64)*VOCAB + colh;
        const float* gp = gates + kh*64;
        #pragma unroll 8
        for (int k=0;k<64;k++) a += gp[k]*wp[k*VOCAB];
        a += __shfl_down(a,1,2);
        if (!kh) out[((size_t)b*VOCAB + colh)*T + t] = a;
      }
      __syncthreads();
    }
  }
}

extern "C" void kernel_launch(void* const* d_in, const int* in_sizes, int n_in,
                              void* d_out, int out_size, void* d_ws, size_t ws_size,
                              hipStream_t stream)
{
  const int*   tokens  = (const int*)d_in[0];
  const float* emb     = (const float*)d_in[1];
  const float* w_ih0   = (const float*)d_in[2];
  const float* w_hh0   = (const float*)d_in[3];
  const float* b_ih0   = (const float*)d_in[4];
  const float* b_hh0   = (const float*)d_in[5];
  const float* w_ih1   = (const float*)d_in[6];
  const float* w_hh1   = (const float*)d_in[7];
  const float* b_ih1   = (const float*)d_in[8];
  const float* b_hh1   = (const float*)d_in[9];
  const float* w_iface = (const float*)d_in[10];
  const float* b_iface = (const float*)d_in[11];
  const float* w_out   = (const float*)d_in[12];
  const float* b_out   = (const float*)d_in[13];
  const float* w_fc    = (const float*)d_in[14];
  const float* b_fc    = (const float*)d_in[15];
  const float* h0      = (const float*)d_in[16];
  float* out = (float*)d_out;
  float* ws  = (float*)d_ws;

  float* xw0     = ws;                  // 512*512   = 262144
  float* whh0T   = xw0     + 262144;    // 128*512
  float* w1catT  = whh0T   + 65536;     // 256*512   = 131072
  float* wifaceT = w1catT  + 131072;    // 128*919   = 117632
  float* woutT   = wifaceT + 117632;    // 640*128   = 81920
  float* wfcT    = woutT   + 81920;     // 128*512
  float* wih0T   = wfcT    + 65536;     // 128*512 (temp)
  float* Ybuf    = wih0T   + 65536;     // 16384*128 = 2097152
  float* stash   = Ybuf    + 2097152;   // 16384*640 = 10485760
  size_t need = (size_t)(262144+65536+131072+117632+81920+65536+65536
                         +2097152+10485760) * 4;
  int defer = (ws_size >= need) ? 1 : 0;

  auto tp = [&](const float* in, float* o, int rows, int cols, int use){
    int total = rows*use;
    k_transpose<<<(total+255)/256, 256, 0, stream>>>(in, o, rows, cols, use);
  };
  tp(w_ih0,   wih0T,          512, 640, 128);
  tp(w_hh0,   whh0T,          512, 128, 128);
  tp(w_ih1,   w1catT,         512, 128, 128);
  tp(w_hh1,   w1catT+128*G4,  512, 128, 128);
  tp(w_iface, wifaceT,        919, 128, 128);
  tp(w_out,   woutT,          128, 640, 640);
  tp(w_fc,    wfcT,           512, 128, 128);
  k_xw0<<<VOCAB, 512, 0, stream>>>(emb, wih0T, b_ih0, b_hh0, xw0);
  k_dnc<<<B, 1024, 0, stream>>>(tokens, xw0, whh0T, w1catT, b_ih1, b_hh1,
                                wifaceT, b_iface, woutT, b_out, wfcT, b_fc,
                                h0, out, stash, defer);
  if (defer){
    k_out<<<(B*T)/16, 512, 0, stream>>>(stash, woutT, b_out, Ybuf);
    k_logits<<<B, 512, 0, stream>>>(Ybuf, w_fc, b_fc, out);
  }
}